// Round 16
// baseline (327.585 us; speedup 1.0000x reference)
//
#include <hip/hip_runtime.h>
#include <hip/hip_bf16.h>

#define N_NODES 50000
#define N_EDGES 800000
#define E_TOT 850000  // edges + self loops, CSR-resident
#define F_IN 32
#define CELL_DIM 16
#define D_IN 48      // F_IN + CELL_DIM
#define X_STRIDE 33  // F_IN + 1 (cell id column)
#define NUM_CELLS 854
#define NEG_SLOPE 0.2f
#define SCAN_BLOCKS 49     // ceil(50000/1024)
#define NODE0_BLOCKS 2048  // node0 part of fused kernel: 8192 waves = 4096 node-streams/head
#define HIST_BLOCKS 3125   // ceil(800000/256)

typedef unsigned int uint;
typedef unsigned short ushort;

// f32 -> bf16 bits, round-to-nearest-even
static __device__ __forceinline__ uint f2b(float f) {
  uint x = __float_as_uint(f);
  return (x + 0x7fffu + ((x >> 16) & 1u)) >> 16;
}
static __device__ __forceinline__ float b2f_lo(uint w) { return __uint_as_float(w << 16); }
static __device__ __forceinline__ float b2f_hi(uint w) { return __uint_as_float(w & 0xffff0000u); }
static __device__ __forceinline__ float lrelu(float e) { return e > 0.f ? e : NEG_SLOPE * e; }

// ---------------- Fused node0 (one wave per node-head) + degree histogram ----------------
// Wave w: head h = w&1 fixed; lane l holds W0 column slice W0[k][h*64+l] in 48 VGPRs.
// Input row staged in registers (lanes 0..32: x row; 32..47: emb), broadcast via shfl.

__global__ __launch_bounds__(256) void k_node0h(const float* __restrict__ x,
                                                const float* __restrict__ emb,
                                                const float* __restrict__ W0,
                                                const float* __restrict__ asrc,
                                                const float* __restrict__ adst,
                                                const int* __restrict__ ei,
                                                ushort* __restrict__ h0u,
                                                float* __restrict__ as0, float* __restrict__ ad0,
                                                int* __restrict__ deg) {
  int tid = threadIdx.x;
  if (blockIdx.x >= NODE0_BLOCKS) {  // histogram part
    int e = (blockIdx.x - NODE0_BLOCKS) * 256 + tid;
    if (e < N_EDGES) atomicAdd(&deg[ei[N_EDGES + e]], 1);
    return;
  }
  int lane = tid & 63, wid = tid >> 6;
  int gw = blockIdx.x * 4 + wid;
  int h = gw & 1;
  float w0r[D_IN];  // 48 VGPRs: this head's W0 column for channel `lane`
#pragma unroll
  for (int k = 0; k < D_IN; ++k) w0r[k] = W0[k * 128 + h * 64 + lane];
  float av_s = asrc[h * 64 + lane], av_d = adst[h * 64 + lane];

  for (int n = gw >> 1; n < N_NODES; n += NODE0_BLOCKS * 2) {
    float t = 0.f;
    if (lane < 33) t = x[n * X_STRIDE + lane];
    int cid = (int)__shfl(t, 32, 64);
    cid = cid < 0 ? 0 : (cid >= NUM_CELLS ? NUM_CELLS - 1 : cid);  // fault guard
    if (lane >= 32 && lane < 48) t = emb[cid * CELL_DIM + (lane - 32)];
    float acc = 0.f;
#pragma unroll
    for (int k = 0; k < D_IN; ++k) acc = fmaf(__shfl(t, k, 64), w0r[k], acc);
    h0u[(n * 64 + lane) * 2 + h] = (ushort)f2b(acc);  // packed half of the bf16x2 word
    float sa = acc * av_s, sd = acc * av_d;
#pragma unroll
    for (int o = 32; o >= 1; o >>= 1) {
      sa += __shfl_xor(sa, o, 64);
      sd += __shfl_xor(sd, o, 64);
    }
    if (lane == 0) {
      as0[n * 2 + h] = sa;
      ad0[n * 2 + h] = sd;
    }
  }
}

// ---------------- CSR scans ----------------

__global__ __launch_bounds__(1024) void k_scan1(const int* __restrict__ deg, int* __restrict__ off,
                                                int* __restrict__ bsum) {
  __shared__ int ws[16];
  int tid = threadIdx.x;
  int lane = tid & 63, wid = tid >> 6;
  int i = blockIdx.x * 1024 + tid;
  int v = (i < N_NODES) ? deg[i] + 1 : 0;  // +1 slot for self-loop
  int sc = v;
#pragma unroll
  for (int o = 1; o < 64; o <<= 1) {
    int t = __shfl_up(sc, o, 64);
    if (lane >= o) sc += t;
  }
  if (lane == 63) ws[wid] = sc;
  __syncthreads();
  if (tid < 16) {
    int w = ws[tid];
    int s = w;
#pragma unroll
    for (int o = 1; o < 16; o <<= 1) {
      int t = __shfl_up(s, o, 64);
      if (tid >= o) s += t;
    }
    ws[tid] = s - w;  // exclusive wave prefix
  }
  __syncthreads();
  int excl = sc - v + ws[wid];
  if (i < N_NODES) off[i] = excl;
  if (tid == 1023) bsum[blockIdx.x] = excl + v;  // block total
}

__global__ __launch_bounds__(1024) void k_scan23(int* __restrict__ off, int* __restrict__ ofs,
                                                 const int* __restrict__ bsum) {
  __shared__ int carry_s;
  int tid = threadIdx.x;
  if (tid < 64) {
    int v = (tid < SCAN_BLOCKS) ? bsum[tid] : 0;
    int s = v;
#pragma unroll
    for (int o = 1; o < 64; o <<= 1) {
      int t = __shfl_up(s, o, 64);
      if (tid >= o) s += t;
    }
    if (tid == (int)blockIdx.x) carry_s = s - v;  // exclusive prefix of this block
  }
  __syncthreads();
  int carry = carry_s;
  int i = blockIdx.x * 1024 + tid;
  if (i < N_NODES) {
    int v = off[i] + carry;
    off[i] = v;
    ofs[i] = v;
  }
  if (i == 0) off[N_NODES] = E_TOT;
}

// slim scatter: CSR slot fill only (weights now inline in agg0); tail fills self-loops
__global__ __launch_bounds__(256) void k_scatter(const int* __restrict__ ei, int* __restrict__ ofs,
                                                 const int* __restrict__ off,
                                                 uint* __restrict__ esrc) {
  int t = blockIdx.x * 256 + threadIdx.x;
  if (t < N_EDGES) {
    int s = ei[t], d = ei[N_EDGES + t];
    int p = atomicAdd(&ofs[d], 1);
    esrc[p] = (uint)s;
  } else if (t < N_EDGES + N_NODES) {
    int n = t - N_EDGES;  // self-loop record in the reserved last slot
    esrc[off[n + 1] - 1] = (uint)n;
  }
}

// ---------------- Fused aggregate L0 (+LN+ELU+linear1+alpha1) ----------------
// One wave per node; 8/4/1 unroll; weights computed inline from L2-resident as0/ad0
// (wave-uniform 8B broadcast per edge + 2 exp in the ~50%-idle VALU).

__global__ __launch_bounds__(256) void k_agg0(const int* __restrict__ off,
                                              const uint* __restrict__ esrc,
                                              const uint* __restrict__ h0p,
                                              const float2* __restrict__ as0v,
                                              const float2* __restrict__ ad0v,
                                              const float* __restrict__ b0,
                                              const float* __restrict__ lng,
                                              const float* __restrict__ lnb,
                                              const float* __restrict__ W1,
                                              const float* __restrict__ asrc1,
                                              const float* __restrict__ adst1,
                                              ushort* __restrict__ h1b,
                                              float* __restrict__ as1, float* __restrict__ ad1) {
  int n = blockIdx.x * 4 + (threadIdx.x >> 6);
  int lane = threadIdx.x & 63;
  float2 adh = ad0v[n];
  float acc0 = 0.f, acc1 = 0.f, den0 = 0.f, den1 = 0.f;
  int i0 = off[n], i1 = off[n + 1];
  int i = i0;
  for (; i + 7 < i1; i += 8) {
    uint s[8];
    float2 a[8];
    uint h[8];
#pragma unroll
    for (int j = 0; j < 8; ++j) s[j] = esrc[i + j];
#pragma unroll
    for (int j = 0; j < 8; ++j) a[j] = as0v[s[j]];
#pragma unroll
    for (int j = 0; j < 8; ++j) h[j] = h0p[s[j] * 64 + lane];
#pragma unroll
    for (int j = 0; j < 8; ++j) {
      float w0 = __expf(lrelu(a[j].x + adh.x));
      float w1 = __expf(lrelu(a[j].y + adh.y));
      acc0 += w0 * b2f_lo(h[j]); den0 += w0;
      acc1 += w1 * b2f_hi(h[j]); den1 += w1;
    }
  }
  for (; i + 3 < i1; i += 4) {
    uint s[4];
    float2 a[4];
    uint h[4];
#pragma unroll
    for (int j = 0; j < 4; ++j) s[j] = esrc[i + j];
#pragma unroll
    for (int j = 0; j < 4; ++j) a[j] = as0v[s[j]];
#pragma unroll
    for (int j = 0; j < 4; ++j) h[j] = h0p[s[j] * 64 + lane];
#pragma unroll
    for (int j = 0; j < 4; ++j) {
      float w0 = __expf(lrelu(a[j].x + adh.x));
      float w1 = __expf(lrelu(a[j].y + adh.y));
      acc0 += w0 * b2f_lo(h[j]); den0 += w0;
      acc1 += w1 * b2f_hi(h[j]); den1 += w1;
    }
  }
  for (; i < i1; ++i) {
    uint s = esrc[i];
    float2 a = as0v[s];
    uint h = h0p[s * 64 + lane];
    float w0 = __expf(lrelu(a.x + adh.x));
    float w1 = __expf(lrelu(a.y + adh.y));
    acc0 += w0 * b2f_lo(h); den0 += w0;
    acc1 += w1 * b2f_hi(h); den1 += w1;
  }
  float v = 0.5f * (acc0 / den0 + acc1 / den1) + b0[lane];
  // LayerNorm across the 64 channels (one wave)
  float mu = v;
#pragma unroll
  for (int o = 32; o >= 1; o >>= 1) mu += __shfl_xor(mu, o, 64);
  mu *= (1.0f / 64.0f);
  float d = v - mu;
  float vr = d * d;
#pragma unroll
  for (int o = 32; o >= 1; o >>= 1) vr += __shfl_xor(vr, o, 64);
  vr *= (1.0f / 64.0f);
  float y = d * rsqrtf(vr + 1e-5f) * lng[lane] + lnb[lane];
  // ELU
  y = y > 0.f ? y : expm1f(y);
  // linear1: h1[c] = sum_k y_k * W1[k,c]
  float h1v = 0.f;
#pragma unroll
  for (int k = 0; k < 64; ++k) {
    float yk = __shfl(y, k, 64);
    h1v += yk * W1[k * 64 + lane];
  }
  h1b[n * 64 + lane] = (ushort)f2b(h1v);
  float sa = h1v * asrc1[lane];
  float sdv = h1v * adst1[lane];
#pragma unroll
  for (int o = 32; o >= 1; o >>= 1) {
    sa += __shfl_xor(sa, o, 64);
    sdv += __shfl_xor(sdv, o, 64);
  }
  if (lane == 0) {
    as1[n] = sa;
    ad1[n] = sdv;
  }
}

// ---------------- Layer 1 aggregate -> output (weights inline; as1 is L2-resident) ----------------

__global__ __launch_bounds__(256) void k_agg1(const int* __restrict__ off,
                                              const uint* __restrict__ esrc,
                                              const ushort* __restrict__ h1b,
                                              const float* __restrict__ as1,
                                              const float* __restrict__ ad1,
                                              const float* __restrict__ b1,
                                              float* __restrict__ out) {
  int n = blockIdx.x * 4 + (threadIdx.x >> 6);
  int lane = threadIdx.x & 63;
  float adv = ad1[n];
  float acc = 0.f, den = 0.f;
  int i0 = off[n], i1 = off[n + 1];
  int i = i0;
  for (; i + 7 < i1; i += 8) {
    uint s[8];
    float a[8];
    uint h[8];
#pragma unroll
    for (int j = 0; j < 8; ++j) s[j] = esrc[i + j];
#pragma unroll
    for (int j = 0; j < 8; ++j) a[j] = as1[s[j]];
#pragma unroll
    for (int j = 0; j < 8; ++j) h[j] = h1b[s[j] * 64 + lane];
#pragma unroll
    for (int j = 0; j < 8; ++j) {
      float w = __expf(lrelu(a[j] + adv));
      acc += w * __uint_as_float(h[j] << 16);
      den += w;
    }
  }
  for (; i + 3 < i1; i += 4) {
    uint s[4];
    float a[4];
    uint h[4];
#pragma unroll
    for (int j = 0; j < 4; ++j) s[j] = esrc[i + j];
#pragma unroll
    for (int j = 0; j < 4; ++j) a[j] = as1[s[j]];
#pragma unroll
    for (int j = 0; j < 4; ++j) h[j] = h1b[s[j] * 64 + lane];
#pragma unroll
    for (int j = 0; j < 4; ++j) {
      float w = __expf(lrelu(a[j] + adv));
      acc += w * __uint_as_float(h[j] << 16);
      den += w;
    }
  }
  for (; i < i1; ++i) {
    uint s = esrc[i];
    float w = __expf(lrelu(as1[s] + adv));
    acc += w * __uint_as_float((uint)h1b[s * 64 + lane] << 16);
    den += w;
  }
  out[n * 64 + lane] = acc / den + b1[lane];
}

// ---------------- host ----------------

extern "C" void kernel_launch(void* const* d_in, const int* in_sizes, int n_in,
                              void* d_out, int out_size, void* d_ws, size_t ws_size,
                              hipStream_t stream) {
  const float* x    = (const float*)d_in[0];
  const int*   ei   = (const int*)d_in[1];
  const float* emb  = (const float*)d_in[2];
  const float* W0   = (const float*)d_in[3];
  const float* as0w = (const float*)d_in[4];
  const float* ad0w = (const float*)d_in[5];
  const float* b0   = (const float*)d_in[6];
  const float* lng  = (const float*)d_in[7];
  const float* lnb  = (const float*)d_in[8];
  const float* W1   = (const float*)d_in[9];
  const float* as1w = (const float*)d_in[10];
  const float* ad1w = (const float*)d_in[11];
  const float* b1   = (const float*)d_in[12];
  float* out = (float*)d_out;

  // workspace layout (8B-aligned arrays first); total ~26 MB
  uint* esrc = (uint*)d_ws;                   // E_TOT
  float* as0 = (float*)(esrc + E_TOT);        // N*2
  float* ad0 = as0 + N_NODES * 2;             // N*2
  float* as1 = ad0 + N_NODES * 2;             // N
  float* ad1 = as1 + N_NODES;                 // N
  uint* h0p = (uint*)(ad1 + N_NODES);         // N*64 (bf16x2 packed; written as ushort halves)
  ushort* h1b = (ushort*)(h0p + N_NODES * 64);  // N*64 bf16
  int* deg  = (int*)(h1b + N_NODES * 64);     // N
  int* off  = deg + N_NODES;                  // N+1
  int* ofs  = off + N_NODES + 1;              // N
  int* bsum = ofs + N_NODES;                  // 64

  hipMemsetAsync(deg, 0, N_NODES * sizeof(int), stream);
  k_node0h<<<NODE0_BLOCKS + HIST_BLOCKS, 256, 0, stream>>>(x, emb, W0, as0w, ad0w, ei,
                                                           (ushort*)h0p, as0, ad0, deg);
  k_scan1<<<SCAN_BLOCKS, 1024, 0, stream>>>(deg, off, bsum);
  k_scan23<<<SCAN_BLOCKS, 1024, 0, stream>>>(off, ofs, bsum);
  k_scatter<<<(N_EDGES + N_NODES + 255) / 256, 256, 0, stream>>>(ei, ofs, off, esrc);
  k_agg0<<<N_NODES / 4, 256, 0, stream>>>(off, esrc, h0p, (const float2*)as0, (const float2*)ad0,
                                          b0, lng, lnb, W1, as1w, ad1w, h1b, as1, ad1);
  k_agg1<<<N_NODES / 4, 256, 0, stream>>>(off, esrc, h1b, as1, ad1, b1, out);
}

// Round 17
// 278.402 us; speedup vs baseline: 1.1767x; 1.1767x over previous
//
#include <hip/hip_runtime.h>
#include <hip/hip_bf16.h>

#define N_NODES 50000
#define N_EDGES 800000
#define E_TOT 850000  // edges + self loops, CSR-resident
#define F_IN 32
#define CELL_DIM 16
#define D_IN 48      // F_IN + CELL_DIM
#define X_STRIDE 33  // F_IN + 1 (cell id column)
#define NUM_CELLS 854
#define NEG_SLOPE 0.2f
#define SCAN_BLOCKS 49     // ceil(50000/1024)
#define NODE0_BLOCKS 2048  // persistent node0 blocks (8 nodes per block-iteration)
#define HIST_BLOCKS 3125   // ceil(800000/256)

typedef unsigned int uint;
typedef unsigned short ushort;

// f32 -> bf16 bits, round-to-nearest-even
static __device__ __forceinline__ uint f2b(float f) {
  uint x = __float_as_uint(f);
  return (x + 0x7fffu + ((x >> 16) & 1u)) >> 16;
}
static __device__ __forceinline__ float b2f_lo(uint w) { return __uint_as_float(w << 16); }
static __device__ __forceinline__ float b2f_hi(uint w) { return __uint_as_float(w & 0xffff0000u); }
static __device__ __forceinline__ float lrelu(float e) { return e > 0.f ? e : NEG_SLOPE * e; }

// ---------------- Fused node0 + degree histogram ----------------
// node0 part: block = 4 waves = 8 nodes/iteration. Wave w: head h=w&1, node-quad q=w>>1.
// Lane l holds W0 column W0[k][h*64+l] in 48 VGPRs (no spill). Input rows staged in LDS
// by each wave (2 rows), read back as wave-uniform float4 broadcasts (no shfl chains).

__global__ __launch_bounds__(256) void k_node0h(const float* __restrict__ x,
                                                const float* __restrict__ emb,
                                                const float* __restrict__ W0,
                                                const float* __restrict__ asrc,
                                                const float* __restrict__ adst,
                                                const int* __restrict__ ei,
                                                ushort* __restrict__ h0u,
                                                float* __restrict__ as0, float* __restrict__ ad0,
                                                int* __restrict__ deg) {
  int tid = threadIdx.x;
  if (blockIdx.x >= NODE0_BLOCKS) {  // histogram part
    int e = (blockIdx.x - NODE0_BLOCKS) * 256 + tid;
    if (e < N_EDGES) atomicAdd(&deg[ei[N_EDGES + e]], 1);
    return;
  }
  __shared__ float hin[8][48];  // 8 node rows; float4 reads are wave-uniform (broadcast)
  int lane = tid & 63, wid = tid >> 6;
  int h = wid & 1;       // head
  int q = wid >> 1;      // node-quad (0: nodes 0-3, 1: nodes 4-7)
  float w0r[D_IN];       // 48 VGPRs: this head's W0 column for channel `lane`
#pragma unroll
  for (int k = 0; k < D_IN; ++k) w0r[k] = W0[k * 128 + h * 64 + lane];
  float av_s = asrc[h * 64 + lane], av_d = adst[h * 64 + lane];

  for (int g = blockIdx.x; g < N_NODES / 8; g += NODE0_BLOCKS) {
    int nb = g * 8;
    // stage: wave w stages rows 2w, 2w+1
#pragma unroll
    for (int j = 0; j < 2; ++j) {
      int loc = 2 * wid + j;
      int n = nb + loc;
      float t = 0.f;
      if (lane < 33) t = x[n * X_STRIDE + lane];
      int cid = (int)__shfl(t, 32, 64);
      cid = cid < 0 ? 0 : (cid >= NUM_CELLS ? NUM_CELLS - 1 : cid);  // fault guard
      if (lane >= 32 && lane < 48) t = emb[cid * CELL_DIM + (lane - 32)];
      if (lane < 48) hin[loc][lane] = t;
    }
    __syncthreads();
    // compute: 4 nodes of my quad, my head, channel = lane
#pragma unroll
    for (int j = 0; j < 4; ++j) {
      int loc = 4 * q + j;
      int n = nb + loc;
      const float4* hp = (const float4*)hin[loc];
      float acc = 0.f;
#pragma unroll
      for (int k4 = 0; k4 < 12; ++k4) {
        float4 hh = hp[k4];
        acc = fmaf(hh.x, w0r[4 * k4 + 0], acc);
        acc = fmaf(hh.y, w0r[4 * k4 + 1], acc);
        acc = fmaf(hh.z, w0r[4 * k4 + 2], acc);
        acc = fmaf(hh.w, w0r[4 * k4 + 3], acc);
      }
      h0u[(n * 64 + lane) * 2 + h] = (ushort)f2b(acc);  // packed half of the bf16x2 word
      float sa = acc * av_s, sd = acc * av_d;
#pragma unroll
      for (int o = 32; o >= 1; o >>= 1) {
        sa += __shfl_xor(sa, o, 64);
        sd += __shfl_xor(sd, o, 64);
      }
      if (lane == 0) {
        as0[n * 2 + h] = sa;
        ad0[n * 2 + h] = sd;
      }
    }
    __syncthreads();  // before restaging
  }
}

// ---------------- CSR scans ----------------

__global__ __launch_bounds__(1024) void k_scan1(const int* __restrict__ deg, int* __restrict__ off,
                                                int* __restrict__ bsum) {
  __shared__ int ws[16];
  int tid = threadIdx.x;
  int lane = tid & 63, wid = tid >> 6;
  int i = blockIdx.x * 1024 + tid;
  int v = (i < N_NODES) ? deg[i] + 1 : 0;  // +1 slot for self-loop
  int sc = v;
#pragma unroll
  for (int o = 1; o < 64; o <<= 1) {
    int t = __shfl_up(sc, o, 64);
    if (lane >= o) sc += t;
  }
  if (lane == 63) ws[wid] = sc;
  __syncthreads();
  if (tid < 16) {
    int w = ws[tid];
    int s = w;
#pragma unroll
    for (int o = 1; o < 16; o <<= 1) {
      int t = __shfl_up(s, o, 64);
      if (tid >= o) s += t;
    }
    ws[tid] = s - w;  // exclusive wave prefix
  }
  __syncthreads();
  int excl = sc - v + ws[wid];
  if (i < N_NODES) off[i] = excl;
  if (tid == 1023) bsum[blockIdx.x] = excl + v;  // block total
}

__global__ __launch_bounds__(1024) void k_scan23(int* __restrict__ off, int* __restrict__ ofs,
                                                 const int* __restrict__ bsum) {
  __shared__ int carry_s;
  int tid = threadIdx.x;
  if (tid < 64) {
    int v = (tid < SCAN_BLOCKS) ? bsum[tid] : 0;
    int s = v;
#pragma unroll
    for (int o = 1; o < 64; o <<= 1) {
      int t = __shfl_up(s, o, 64);
      if (tid >= o) s += t;
    }
    if (tid == (int)blockIdx.x) carry_s = s - v;  // exclusive prefix of this block
  }
  __syncthreads();
  int carry = carry_s;
  int i = blockIdx.x * 1024 + tid;
  if (i < N_NODES) {
    int v = off[i] + carry;
    off[i] = v;
    ofs[i] = v;
  }
  if (i == 0) off[N_NODES] = E_TOT;
}

// scatter edges into CSR slots + compute layer-0 attention weights; tail fills self-loops
__global__ __launch_bounds__(256) void k_scatter(const int* __restrict__ ei, int* __restrict__ ofs,
                                                 const int* __restrict__ off,
                                                 const float2* __restrict__ as0v,
                                                 const float2* __restrict__ ad0v,
                                                 uint2* __restrict__ ew) {
  int t = blockIdx.x * 256 + threadIdx.x;
  if (t < N_EDGES) {
    int s = ei[t], d = ei[N_EDGES + t];
    float2 a_s = as0v[s], a_d = ad0v[d];
    float w0 = __expf(lrelu(a_s.x + a_d.x));
    float w1 = __expf(lrelu(a_s.y + a_d.y));
    int p = atomicAdd(&ofs[d], 1);
    ew[p] = make_uint2((uint)s, f2b(w0) | (f2b(w1) << 16));
  } else if (t < N_EDGES + N_NODES) {
    int n = t - N_EDGES;  // self-loop record in the reserved last slot
    int slot = off[n + 1] - 1;
    float2 a_s = as0v[n], a_d = ad0v[n];
    float w0 = __expf(lrelu(a_s.x + a_d.x));
    float w1 = __expf(lrelu(a_s.y + a_d.y));
    ew[slot] = make_uint2((uint)n, f2b(w0) | (f2b(w1) << 16));
  }
}

// ---------------- Fused aggregate L0 (+LN+ELU+linear1+alpha1) — R10 known-best ----------------

__global__ __launch_bounds__(256) void k_agg0(const int* __restrict__ off,
                                              const uint2* __restrict__ ew,
                                              const uint* __restrict__ h0p,
                                              const float* __restrict__ b0,
                                              const float* __restrict__ lng,
                                              const float* __restrict__ lnb,
                                              const float* __restrict__ W1,
                                              const float* __restrict__ asrc1,
                                              const float* __restrict__ adst1,
                                              ushort* __restrict__ h1b,
                                              float* __restrict__ as1, float* __restrict__ ad1) {
  int n = blockIdx.x * 4 + (threadIdx.x >> 6);
  int lane = threadIdx.x & 63;
  float acc0 = 0.f, acc1 = 0.f, den0 = 0.f, den1 = 0.f;
  int i0 = off[n], i1 = off[n + 1];
  int i = i0;
  for (; i + 7 < i1; i += 8) {
    uint2 r[8];
    uint h[8];
#pragma unroll
    for (int j = 0; j < 8; ++j) r[j] = ew[i + j];
#pragma unroll
    for (int j = 0; j < 8; ++j) h[j] = h0p[r[j].x * 64 + lane];
#pragma unroll
    for (int j = 0; j < 8; ++j) {
      float w;
      w = b2f_lo(r[j].y); acc0 += w * b2f_lo(h[j]); den0 += w;
      w = b2f_hi(r[j].y); acc1 += w * b2f_hi(h[j]); den1 += w;
    }
  }
  for (; i + 3 < i1; i += 4) {
    uint2 r[4];
    uint h[4];
#pragma unroll
    for (int j = 0; j < 4; ++j) r[j] = ew[i + j];
#pragma unroll
    for (int j = 0; j < 4; ++j) h[j] = h0p[r[j].x * 64 + lane];
#pragma unroll
    for (int j = 0; j < 4; ++j) {
      float w;
      w = b2f_lo(r[j].y); acc0 += w * b2f_lo(h[j]); den0 += w;
      w = b2f_hi(r[j].y); acc1 += w * b2f_hi(h[j]); den1 += w;
    }
  }
  for (; i < i1; ++i) {
    uint2 r = ew[i];
    uint h = h0p[r.x * 64 + lane];
    float w;
    w = b2f_lo(r.y); acc0 += w * b2f_lo(h); den0 += w;
    w = b2f_hi(r.y); acc1 += w * b2f_hi(h); den1 += w;
  }
  float v = 0.5f * (acc0 / den0 + acc1 / den1) + b0[lane];
  // LayerNorm across the 64 channels (one wave)
  float mu = v;
#pragma unroll
  for (int o = 32; o >= 1; o >>= 1) mu += __shfl_xor(mu, o, 64);
  mu *= (1.0f / 64.0f);
  float d = v - mu;
  float vr = d * d;
#pragma unroll
  for (int o = 32; o >= 1; o >>= 1) vr += __shfl_xor(vr, o, 64);
  vr *= (1.0f / 64.0f);
  float y = d * rsqrtf(vr + 1e-5f) * lng[lane] + lnb[lane];
  // ELU
  y = y > 0.f ? y : expm1f(y);
  // linear1: h1[c] = sum_k y_k * W1[k,c]
  float h1v = 0.f;
#pragma unroll
  for (int k = 0; k < 64; ++k) {
    float yk = __shfl(y, k, 64);
    h1v += yk * W1[k * 64 + lane];
  }
  h1b[n * 64 + lane] = (ushort)f2b(h1v);
  float sa = h1v * asrc1[lane];
  float sdv = h1v * adst1[lane];
#pragma unroll
  for (int o = 32; o >= 1; o >>= 1) {
    sa += __shfl_xor(sa, o, 64);
    sdv += __shfl_xor(sdv, o, 64);
  }
  if (lane == 0) {
    as1[n] = sa;
    ad1[n] = sdv;
  }
}

// ---------------- Layer 1 aggregate -> output (weights inline; as1 is L2-resident) ----------------

__global__ __launch_bounds__(256) void k_agg1(const int* __restrict__ off,
                                              const uint2* __restrict__ ew,
                                              const ushort* __restrict__ h1b,
                                              const float* __restrict__ as1,
                                              const float* __restrict__ ad1,
                                              const float* __restrict__ b1,
                                              float* __restrict__ out) {
  int n = blockIdx.x * 4 + (threadIdx.x >> 6);
  int lane = threadIdx.x & 63;
  float adv = ad1[n];
  float acc = 0.f, den = 0.f;
  int i0 = off[n], i1 = off[n + 1];
  int i = i0;
  for (; i + 7 < i1; i += 8) {
    uint s[8];
    float a[8];
    uint h[8];
#pragma unroll
    for (int j = 0; j < 8; ++j) s[j] = ew[i + j].x;
#pragma unroll
    for (int j = 0; j < 8; ++j) a[j] = as1[s[j]];
#pragma unroll
    for (int j = 0; j < 8; ++j) h[j] = h1b[s[j] * 64 + lane];
#pragma unroll
    for (int j = 0; j < 8; ++j) {
      float w = __expf(lrelu(a[j] + adv));
      acc += w * __uint_as_float(h[j] << 16);
      den += w;
    }
  }
  for (; i + 3 < i1; i += 4) {
    uint s[4];
    float a[4];
    uint h[4];
#pragma unroll
    for (int j = 0; j < 4; ++j) s[j] = ew[i + j].x;
#pragma unroll
    for (int j = 0; j < 4; ++j) a[j] = as1[s[j]];
#pragma unroll
    for (int j = 0; j < 4; ++j) h[j] = h1b[s[j] * 64 + lane];
#pragma unroll
    for (int j = 0; j < 4; ++j) {
      float w = __expf(lrelu(a[j] + adv));
      acc += w * __uint_as_float(h[j] << 16);
      den += w;
    }
  }
  for (; i < i1; ++i) {
    uint s = ew[i].x;
    float w = __expf(lrelu(as1[s] + adv));
    acc += w * __uint_as_float((uint)h1b[s * 64 + lane] << 16);
    den += w;
  }
  out[n * 64 + lane] = acc / den + b1[lane];
}

// ---------------- host ----------------

extern "C" void kernel_launch(void* const* d_in, const int* in_sizes, int n_in,
                              void* d_out, int out_size, void* d_ws, size_t ws_size,
                              hipStream_t stream) {
  const float* x    = (const float*)d_in[0];
  const int*   ei   = (const int*)d_in[1];
  const float* emb  = (const float*)d_in[2];
  const float* W0   = (const float*)d_in[3];
  const float* as0w = (const float*)d_in[4];
  const float* ad0w = (const float*)d_in[5];
  const float* b0   = (const float*)d_in[6];
  const float* lng  = (const float*)d_in[7];
  const float* lnb  = (const float*)d_in[8];
  const float* W1   = (const float*)d_in[9];
  const float* as1w = (const float*)d_in[10];
  const float* ad1w = (const float*)d_in[11];
  const float* b1   = (const float*)d_in[12];
  float* out = (float*)d_out;

  // workspace layout (8B-aligned arrays first); total ~29 MB
  uint2* ew  = (uint2*)d_ws;                  // E_TOT {src, bf16x2 w0|w1}
  float* as0 = (float*)(ew + E_TOT);          // N*2
  float* ad0 = as0 + N_NODES * 2;             // N*2
  float* as1 = ad0 + N_NODES * 2;             // N
  float* ad1 = as1 + N_NODES;                 // N
  uint* h0p = (uint*)(ad1 + N_NODES);         // N*64 (bf16x2 packed; written as ushort halves)
  ushort* h1b = (ushort*)(h0p + N_NODES * 64);  // N*64 bf16
  int* deg  = (int*)(h1b + N_NODES * 64);     // N
  int* off  = deg + N_NODES;                  // N+1
  int* ofs  = off + N_NODES + 1;              // N
  int* bsum = ofs + N_NODES;                  // 64

  hipMemsetAsync(deg, 0, N_NODES * sizeof(int), stream);
  k_node0h<<<NODE0_BLOCKS + HIST_BLOCKS, 256, 0, stream>>>(x, emb, W0, as0w, ad0w, ei,
                                                           (ushort*)h0p, as0, ad0, deg);
  k_scan1<<<SCAN_BLOCKS, 1024, 0, stream>>>(deg, off, bsum);
  k_scan23<<<SCAN_BLOCKS, 1024, 0, stream>>>(off, ofs, bsum);
  k_scatter<<<(N_EDGES + N_NODES + 255) / 256, 256, 0, stream>>>(ei, ofs, off, (const float2*)as0,
                                                                 (const float2*)ad0, ew);
  k_agg0<<<N_NODES / 4, 256, 0, stream>>>(off, ew, h0p, b0, lng, lnb, W1, as1w, ad1w,
                                          h1b, as1, ad1);
  k_agg1<<<N_NODES / 4, 256, 0, stream>>>(off, ew, h1b, as1, ad1, b1, out);
}